// Round 15
// baseline (177.716 us; speedup 1.0000x reference)
//
#include <hip/hip_runtime.h>
#include <cstdint>
#include <cstddef>

#define B    8
#define SEQ  2048
#define H    4
#define DKN  5
#define DIM  20
#define PRE8 8
#define SENTB ((short)0xC6E0) // bf16(-28672): huge negative score -> P bits = 0
#define ONEB  ((short)0x3F80) // bf16(1.0)
#define B128  ((short)0x4300) // bf16(128.0) - Q bias slot (x128 folded into scores)
#define PBIAS 16250.5f        // 127*128 (bf16 exp bias << 7) minus minimax shift

typedef short short8 __attribute__((ext_vector_type(8)));
typedef float f32x16 __attribute__((ext_vector_type(16)));

static __device__ __forceinline__ unsigned short bf16b(float x) {
    union { float f; unsigned u; } v; v.f = x;
    unsigned r = v.u + 0x7FFFu + ((v.u >> 16) & 1u);   // RTNE
    return (unsigned short)(r >> 16);
}
static __device__ __forceinline__ float bf16f(unsigned short h) {
    union { unsigned u; float f; } v; v.u = ((unsigned)h) << 16;
    return v.f;
}
// R15: Schraudolph-to-bf16. t = 128*score + PBIAS (computed BY the MFMA via C-init).
// max(t,0) kills sentinel/underflow; int-trunc's low 16 bits ARE bf16(2^score) (+/-3%).
// One v_perm packs two P values.
static __device__ __forceinline__ unsigned pk_pbits(float ta, float tb) {
    unsigned ia = (unsigned)(int)fmaxf(ta, 0.f);
    unsigned ib = (unsigned)(int)fmaxf(tb, 0.f);
    return __builtin_amdgcn_perm(ib, ia, 0x05040100u);  // {lo16(ib),lo16(ia)}
}
// key offset t (0..31) -> Vt physical column slot (32x32x16 PV k-slot inverse)
static __device__ __forceinline__ int sig32(int t) {
    return (t & 19) | ((t & 4) << 1) | ((t & 8) >> 1);
}

// ws layout:
//   Qt : short [x][b][h][s][16]   hi(0..7, [5]=128 bias) | lo(8..15, [5]=0)  6 MB
//   Kt : short [x][b][h][c][8]    compacted keys; c>=cnt sentinel            3 MB
//   Vt : short [x][b][h][8][SEQ]  transposed values at sig32 columns; r5=1   3 MB
//   pre : float [p][b][h][s][8]                                             12.6 MB
//   meta: int [B]

// ---------------- projections + in-block windowed compaction ----------------
__global__ __launch_bounds__(256) void proj_kernel(
    const float* __restrict__ q, const float* __restrict__ k, const float* __restrict__ v,
    const float* __restrict__ W0, const float* __restrict__ b0,
    const float* __restrict__ W1, const float* __restrict__ b1,
    const float* __restrict__ W2, const float* __restrict__ b2,
    const int* __restrict__ mask,
    short* __restrict__ Qt, short* __restrict__ Kt, short* __restrict__ Vt,
    int* __restrict__ meta)
{
    __shared__ float Ws[3][DIM * DIM];
    __shared__ float bsh[3][DIM];
    __shared__ int   widx[256];
    __shared__ int   cntS;

    int tid = threadIdx.x;
    int blk = blockIdx.x;            // 3*8*4*8 = 768
    int w   = blk & 7;  blk >>= 3;   // s-window
    int h   = blk & 3;  blk >>= 2;
    int bb  = blk & 7;  blk >>= 3;
    int x   = blk;                   // 0..2
    int s0  = w * 256;

    for (int i = tid; i < DIM * DIM; i += 256) {
        Ws[0][i] = W0[i]; Ws[1][i] = W1[i]; Ws[2][i] = W2[i];
    }
    if (tid < DIM) { bsh[0][tid] = b0[tid]; bsh[1][tid] = b1[tid]; bsh[2][tid] = b2[tid]; }

    // wave 0: scan mask[bb], record gather indices for compacted window [s0,s0+256)
    if (tid < 64) {
        const int* mrow = mask + bb * SEQ;
        int base = 0;
        for (int ch = 0; ch < SEQ; ch += 64) {
            int mv = mrow[ch + tid];
            unsigned long long bal = __ballot(mv != 0);
            int pos = base + (int)__popcll(bal & ((1ull << tid) - 1ull));
            if (mv && pos >= s0 && pos < s0 + 256) widx[pos - s0] = ch + tid;
            base += (int)__popcll(bal);
        }
        if (tid == 0) {
            cntS = base;
            if (x == 0 && h == 0 && w == 0) meta[bb] = base;
        }
    }
    __syncthreads();

    int  cnt   = cntS;
    int  c     = s0 + tid;
    bool valid = c < cnt;
    int  gs    = valid ? widx[tid] : 0;

    // (1/sqrt5)*log2(e)*128 — the x128 makes MFMA emit Schraudolph's 128*x directly
    const float QSC = 0.44721359549995793f * 1.4426950408889634f * 128.0f;
    const float* base = (x == 0) ? q : ((x == 1) ? k : v);

    float xq[DIM], xg[DIM];
    {
        const float4* r4 = (const float4*)(base + (size_t)(bb * SEQ + c) * DIM);
        const float4* g4 = (const float4*)(base + (size_t)(bb * SEQ + gs) * DIM);
        #pragma unroll
        for (int i = 0; i < 5; ++i) {
            float4 a = r4[i], g = g4[i];
            xq[i*4+0]=a.x; xq[i*4+1]=a.y; xq[i*4+2]=a.z; xq[i*4+3]=a.w;
            xg[i*4+0]=g.x; xg[i*4+1]=g.y; xg[i*4+2]=g.z; xg[i*4+3]=g.w;
        }
    }

    #define DOT20(xv, t, j, dst) {                                        \
        float acc_ = bsh[t][j];                                           \
        const float4* wr_ = (const float4*)&Ws[t][(j) * DIM];             \
        _Pragma("unroll")                                                 \
        for (int i4 = 0; i4 < 5; ++i4) {                                  \
            float4 w_ = wr_[i4];                                          \
            acc_ += (xv)[i4*4+0]*w_.x + (xv)[i4*4+1]*w_.y                 \
                  + (xv)[i4*4+2]*w_.z + (xv)[i4*4+3]*w_.w;                \
        }                                                                 \
        dst = acc_;                                                       \
    }

    size_t row = ((size_t)(x * B + bb) * H + h) * SEQ + c;

    // Q-role (W0): pre-scaled (incl. x128), hi/lo bf16 split; hi[5]=128 (bias), lo[5]=0
    short8 qhi = {0, 0, 0, 0, 0, B128, 0, 0};
    short8 qlo = {0, 0, 0, 0, 0, 0, 0, 0};
    #pragma unroll
    for (int d = 0; d < DKN; ++d) {
        float y; DOT20(xq, 0, h * DKN + d, y);
        y *= QSC;
        unsigned short hb = bf16b(y);
        qhi[d] = (short)hb;
        qlo[d] = (short)bf16b(y - bf16f(hb));
    }
    ((short8*)Qt)[row * 2 + 0] = qhi;
    ((short8*)Qt)[row * 2 + 1] = qlo;

    // K-role (W1) on gathered key row, or sentinel ([5]=-28672*128 via bias -> P=0)
    short8 rk = {0, 0, 0, 0, 0, valid ? (short)0 : SENTB, 0, 0};
    if (valid) {
        #pragma unroll
        for (int d = 0; d < DKN; ++d) {
            float y; DOT20(xg, 1, h * DKN + d, y);
            rk[d] = (short)bf16b(y);
        }
    }
    ((short8*)Kt)[row] = rk;

    // V-role (W2): transposed store at sig32-permuted column; row5 = 1 (l-col)
    if (valid) {
        size_t vb = ((size_t)(x * B + bb) * H + h) * 8 * SEQ;
        int vcol = (c & ~31) + sig32(c & 31);
        #pragma unroll
        for (int d = 0; d < DKN; ++d) {
            float y; DOT20(xg, 2, h * DKN + d, y);
            Vt[vb + (size_t)d * SEQ + vcol] = (short)bf16b(y);
        }
        Vt[vb + (size_t)5 * SEQ + vcol] = ONEB;
    }
}

// ---------------- barrier-free MFMA flash attention (32x32x16 S^T form) ----------------
// 2 waves/block; each wave: 2 q-tiles interleaved, 64-key unrolled k-loop.
// Score MFMA C-init = PBIAS -> D = 128*score + PBIAS = Schraudolph input.
__global__ __launch_bounds__(128) void attn_kernel(
    const short* __restrict__ Qt, const short* __restrict__ Kt,
    const short* __restrict__ Vt, const int* __restrict__ meta,
    float* __restrict__ pre)
{
    int lane = threadIdx.x & 63;
    int l31  = lane & 31, half = lane >> 5;

    int lin = blockIdx.x * 2 + (threadIdx.x >> 6);   // 3072*2 = 6144 waves
    int qt  = lin & 31; lin >>= 5;
    int h   = lin & 3;  lin >>= 2;
    int b   = lin & 7;  lin >>= 3;
    int p   = lin;
    int a   = (0x212010 >> (4 * p)) & 0xF;   // Q source
    int kv  = (0x120201 >> (4 * p)) & 0xF;   // K/V source

    int cnt  = meta[b];
    int kend = (cnt + 63) & ~63;             // 64-aligned; sentinel K rows pad

    const short*  Qb = Qt + ((size_t)(a  * B + b) * H + h) * SEQ * 16;
    const short8* Kb = (const short8*)Kt + ((size_t)(kv * B + b) * H + h) * SEQ;
    const short*  Vb = Vt + ((size_t)(kv * B + b) * H + h) * 8 * SEQ;
    const short*  Vr = Vb + (size_t)(l31 & 7) * SEQ + half * 8;

    int qb0 = qt * 32, qb1 = qt * 32 + 1024;
    // B-frag Q: B[n=q=l31][k=half*8+j]; half0 = Q-hi (k0-7), half1 = Q-lo (k8-15)
    short8 qf0 = *(const short8*)(Qb + (size_t)(qb0 + l31) * 16 + half * 8);
    short8 qf1 = *(const short8*)(Qb + (size_t)(qb1 + l31) * 16 + half * 8);

    f32x16 zc = {0.f,0.f,0.f,0.f,0.f,0.f,0.f,0.f,0.f,0.f,0.f,0.f,0.f,0.f,0.f,0.f};
    f32x16 sb = {PBIAS,PBIAS,PBIAS,PBIAS,PBIAS,PBIAS,PBIAS,PBIAS,
                 PBIAS,PBIAS,PBIAS,PBIAS,PBIAS,PBIAS,PBIAS,PBIAS};
    f32x16 acc0 = zc, acc1 = zc;

    // prefetch iteration 0 (64 keys: sub-steps A and B)
    short8 kfA = Kb[l31],      kfB = Kb[32 + l31];
    short8 vaA = *(const short8*)(Vr);
    short8 vcA = *(const short8*)(Vr + 16);
    short8 vaB = *(const short8*)(Vr + 32);
    short8 vcB = *(const short8*)(Vr + 48);

    for (int c0 = 0; c0 < kend; c0 += 64) {
        int c1 = c0 + 64;   // final prefetch reads stray in-ws bytes, never consumed
        short8 kfA_n = Kb[c1 + l31];
        short8 kfB_n = Kb[c1 + 32 + l31];
        short8 vaA_n = *(const short8*)(Vr + c1);
        short8 vcA_n = *(const short8*)(Vr + c1 + 16);
        short8 vaB_n = *(const short8*)(Vr + c1 + 32);
        short8 vcB_n = *(const short8*)(Vr + c1 + 48);

        // S^T+bias: D = 128*score + PBIAS; col=q=l31, key=(reg&3)+8*(reg>>2)+4*half
        f32x16 dA0 = __builtin_amdgcn_mfma_f32_32x32x16_bf16(kfA, qf0, sb, 0, 0, 0);
        f32x16 dA1 = __builtin_amdgcn_mfma_f32_32x32x16_bf16(kfA, qf1, sb, 0, 0, 0);
        f32x16 dB0 = __builtin_amdgcn_mfma_f32_32x32x16_bf16(kfB, qf0, sb, 0, 0, 0);
        f32x16 dB1 = __builtin_amdgcn_mfma_f32_32x32x16_bf16(kfB, qf1, sb, 0, 0, 0);

        // Schraudolph: max+cvt+perm only — no transcendental.
        unsigned pA00[4], pA01[4], pA10[4], pA11[4];
        unsigned pB00[4], pB01[4], pB10[4], pB11[4];
        #pragma unroll
        for (int r = 0; r < 4; ++r) {
            pA00[r] = pk_pbits(dA0[2 * r], dA0[2 * r + 1]);
            pA01[r] = pk_pbits(dA0[2 * r + 8], dA0[2 * r + 9]);
            pA10[r] = pk_pbits(dA1[2 * r], dA1[2 * r + 1]);
            pA11[r] = pk_pbits(dA1[2 * r + 8], dA1[2 * r + 9]);
            pB00[r] = pk_pbits(dB0[2 * r], dB0[2 * r + 1]);
            pB01[r] = pk_pbits(dB0[2 * r + 8], dB0[2 * r + 9]);
            pB10[r] = pk_pbits(dB1[2 * r], dB1[2 * r + 1]);
            pB11[r] = pk_pbits(dB1[2 * r + 8], dB1[2 * r + 9]);
        }
        short8 fA00, fA01, fA10, fA11, fB00, fB01, fB10, fB11;
        __builtin_memcpy(&fA00, pA00, 16); __builtin_memcpy(&fA01, pA01, 16);
        __builtin_memcpy(&fA10, pA10, 16); __builtin_memcpy(&fA11, pA11, 16);
        __builtin_memcpy(&fB00, pB00, 16); __builtin_memcpy(&fB01, pB01, 16);
        __builtin_memcpy(&fB10, pB10, 16); __builtin_memcpy(&fB11, pB11, 16);

        // O^T: A=V^T[m=dim][k-slot], B=P[n=q][k-slot]; Vt row5=1 -> row5 of D = l
        acc0 = __builtin_amdgcn_mfma_f32_32x32x16_bf16(vaA, fA00, acc0, 0, 0, 0);
        acc1 = __builtin_amdgcn_mfma_f32_32x32x16_bf16(vaA, fA10, acc1, 0, 0, 0);
        acc0 = __builtin_amdgcn_mfma_f32_32x32x16_bf16(vcA, fA01, acc0, 0, 0, 0);
        acc1 = __builtin_amdgcn_mfma_f32_32x32x16_bf16(vcA, fA11, acc1, 0, 0, 0);
        acc0 = __builtin_amdgcn_mfma_f32_32x32x16_bf16(vaB, fB00, acc0, 0, 0, 0);
        acc1 = __builtin_amdgcn_mfma_f32_32x32x16_bf16(vaB, fB10, acc1, 0, 0, 0);
        acc0 = __builtin_amdgcn_mfma_f32_32x32x16_bf16(vcB, fB01, acc0, 0, 0, 0);
        acc1 = __builtin_amdgcn_mfma_f32_32x32x16_bf16(vcB, fB11, acc1, 0, 0, 0);

        kfA = kfA_n; kfB = kfB_n;
        vaA = vaA_n; vcA = vcA_n; vaB = vaB_n; vcB = vcB_n;
    }

    // D rows: dim0-3 = half0 regs 0-3; dim4 = half1 reg0; l (row5) = half1 reg1
    float* base0 = pre + (((size_t)p * B + b) * H + h) * SEQ * PRE8;
    {
        float lv  = __shfl(acc0[1], 32 + l31, 64);
        float inv = 1.0f / lv;
        float* dst = base0 + (size_t)(qb0 + l31) * PRE8;
        if (half == 0)
            *(float4*)dst = make_float4(acc0[0]*inv, acc0[1]*inv, acc0[2]*inv, acc0[3]*inv);
        else
            dst[4] = acc0[0] * inv;
    }
    {
        float lv  = __shfl(acc1[1], 32 + l31, 64);
        float inv = 1.0f / lv;
        float* dst = base0 + (size_t)(qb1 + l31) * PRE8;
        if (half == 0)
            *(float4*)dst = make_float4(acc1[0]*inv, acc1[1]*inv, acc1[2]*inv, acc1[3]*inv);
        else
            dst[4] = acc1[0] * inv;
    }
}

// ---------------- sum 6 pairs + output projection ----------------
__global__ __launch_bounds__(256) void final_kernel(
    const float* __restrict__ pre,
    const float* __restrict__ W3, const float* __restrict__ b3,
    float* __restrict__ out)
{
    __shared__ float Ws[DIM * DIM];
    __shared__ float bs[DIM];
    int tid = threadIdx.x;
    for (int i = tid; i < DIM * DIM; i += 256) Ws[i] = W3[i];
    if (tid < DIM) bs[tid] = b3[tid];
    __syncthreads();

    int g = blockIdx.x * 256 + tid;      // B*SEQ = 16384 exactly
    int b = g / SEQ;
    int s = g - b * SEQ;

    float x[DIM];
    #pragma unroll
    for (int i = 0; i < DIM; ++i) x[i] = 0.f;

    for (int p = 0; p < 6; ++p) {
        #pragma unroll
        for (int h = 0; h < H; ++h) {
            const float* sr = pre + (((size_t)p * B + b) * H + h) * SEQ * PRE8
                                  + (size_t)s * PRE8;
            float4 a = *(const float4*)sr;
            float  a4 = sr[4];
            x[h * DKN + 0] += a.x; x[h * DKN + 1] += a.y; x[h * DKN + 2] += a.z;
            x[h * DKN + 3] += a.w; x[h * DKN + 4] += a4;
        }
    }

    float y[DIM];
    for (int j = 0; j < DIM; ++j) {
        float acc = bs[j];
        const float4* wr = (const float4*)&Ws[j * DIM];
        #pragma unroll
        for (int i4 = 0; i4 < 5; ++i4) {
            float4 w = wr[i4];
            acc += x[i4*4+0]*w.x + x[i4*4+1]*w.y + x[i4*4+2]*w.z + x[i4*4+3]*w.w;
        }
        y[j] = acc;
    }
    float4* dst = (float4*)(out + (size_t)(b * SEQ + s) * DIM);
    #pragma unroll
    for (int j4 = 0; j4 < 5; ++j4)
        dst[j4] = make_float4(y[j4*4+0], y[j4*4+1], y[j4*4+2], y[j4*4+3]);
}

extern "C" void kernel_launch(void* const* d_in, const int* in_sizes, int n_in,
                              void* d_out, int out_size, void* d_ws, size_t ws_size,
                              hipStream_t stream) {
    const float* q    = (const float*)d_in[0];
    const float* k    = (const float*)d_in[1];
    const float* v    = (const float*)d_in[2];
    const int*   mask = (const int*)d_in[3];
    const float* W0 = (const float*)d_in[4];  const float* b0 = (const float*)d_in[5];
    const float* W1 = (const float*)d_in[6];  const float* b1 = (const float*)d_in[7];
    const float* W2 = (const float*)d_in[8];  const float* b2 = (const float*)d_in[9];
    const float* W3 = (const float*)d_in[10]; const float* b3 = (const float*)d_in[11];

    const size_t NROW = (size_t)3 * B * H * SEQ;       // 196608
    short* Qt = (short*)d_ws;                          // NROW*16 shorts (6 MB)
    short* Kt = Qt + NROW * 16;                        // NROW*8 shorts  (3 MB)
    short* Vt = Kt + NROW * 8;                         // NROW*8 shorts  (3 MB)
    float* pre = (float*)(Vt + NROW * 8);              // 6*B*H*SEQ*8 floats (12.6 MB)
    int*   meta = (int*)(pre + (size_t)6 * B * H * SEQ * PRE8);
    float* out = (float*)d_out;

    proj_kernel<<<dim3(3 * B * H * (SEQ / 256)), dim3(256), 0, stream>>>(
        q, k, v, W0, b0, W1, b1, W2, b2, mask, Qt, Kt, Vt, meta);
    attn_kernel<<<dim3(6 * B * H * 32 / 2), dim3(128), 0, stream>>>(
        Qt, Kt, Vt, meta, pre);
    final_kernel<<<dim3(B * SEQ / 256), dim3(256), 0, stream>>>(pre, W3, b3, out);
}

// Round 16
// 162.288 us; speedup vs baseline: 1.0951x; 1.0951x over previous
//
#include <hip/hip_runtime.h>
#include <cstdint>
#include <cstddef>

#define B    8
#define SEQ  2048
#define H    4
#define DKN  5
#define DIM  20
#define PRE8 8
#define SENTB ((short)0xC2FC) // bf16(-126): sentinel bias product -> t=122 -> P bits ~ 0
#define ONEB  ((short)0x3F80) // bf16(1.0)
#define B128  ((short)0x4300) // bf16(128.0) - Q bias slot (x128 folded into scores)
// MAGIC (2^23 sticky-int) + Schraudolph bias (127*128 - minimax shift).
// D = MAGIC + 128*score + 16250 stays in [2^23,2^24): low16 bits of D ARE bf16(2^score).
#define PBIASM 12599162.0f

typedef short short8 __attribute__((ext_vector_type(8)));
typedef float f32x16 __attribute__((ext_vector_type(16)));

static __device__ __forceinline__ unsigned short bf16b(float x) {
    union { float f; unsigned u; } v; v.f = x;
    unsigned r = v.u + 0x7FFFu + ((v.u >> 16) & 1u);   // RTNE
    return (unsigned short)(r >> 16);
}
static __device__ __forceinline__ float bf16f(unsigned short h) {
    union { unsigned u; float f; } v; v.u = ((unsigned)h) << 16;
    return v.f;
}
// R16: P-gen = ONE v_perm per pair. D-reg low16 bits are already the bf16 P value
// (exp+cvt folded into the MFMA C-init magic constant). No trans/quarter-pipe ops.
static __device__ __forceinline__ unsigned pk_pbits(float ta, float tb) {
    unsigned ia, ib;
    __builtin_memcpy(&ia, &ta, 4);
    __builtin_memcpy(&ib, &tb, 4);
    return __builtin_amdgcn_perm(ib, ia, 0x05040100u);  // {lo16(ib), lo16(ia)}
}
// key offset t (0..31) -> Vt physical column slot (32x32x16 PV k-slot inverse)
static __device__ __forceinline__ int sig32(int t) {
    return (t & 19) | ((t & 4) << 1) | ((t & 8) >> 1);
}

// ws layout:
//   Qt : short [x][b][h][s][16]   hi(0..7, [5]=128 bias) | lo(8..15, [5]=0)  6 MB
//   Kt : short [x][b][h][c][8]    compacted keys; c>=cnt sentinel            3 MB
//   Vt : short [x][b][h][8][SEQ]  transposed values at sig32 columns; r5=1   3 MB
//   pre : float [p][b][h][s][8]                                             12.6 MB
//   meta: int [B]

// ---------------- projections + in-block windowed compaction ----------------
__global__ __launch_bounds__(256) void proj_kernel(
    const float* __restrict__ q, const float* __restrict__ k, const float* __restrict__ v,
    const float* __restrict__ W0, const float* __restrict__ b0,
    const float* __restrict__ W1, const float* __restrict__ b1,
    const float* __restrict__ W2, const float* __restrict__ b2,
    const int* __restrict__ mask,
    short* __restrict__ Qt, short* __restrict__ Kt, short* __restrict__ Vt,
    int* __restrict__ meta)
{
    __shared__ float Ws[3][DIM * DIM];
    __shared__ float bsh[3][DIM];
    __shared__ int   widx[256];
    __shared__ int   cntS;

    int tid = threadIdx.x;
    int blk = blockIdx.x;            // 3*8*4*8 = 768
    int w   = blk & 7;  blk >>= 3;   // s-window
    int h   = blk & 3;  blk >>= 2;
    int bb  = blk & 7;  blk >>= 3;
    int x   = blk;                   // 0..2
    int s0  = w * 256;

    for (int i = tid; i < DIM * DIM; i += 256) {
        Ws[0][i] = W0[i]; Ws[1][i] = W1[i]; Ws[2][i] = W2[i];
    }
    if (tid < DIM) { bsh[0][tid] = b0[tid]; bsh[1][tid] = b1[tid]; bsh[2][tid] = b2[tid]; }

    // wave 0: scan mask[bb], record gather indices for compacted window [s0,s0+256)
    if (tid < 64) {
        const int* mrow = mask + bb * SEQ;
        int base = 0;
        for (int ch = 0; ch < SEQ; ch += 64) {
            int mv = mrow[ch + tid];
            unsigned long long bal = __ballot(mv != 0);
            int pos = base + (int)__popcll(bal & ((1ull << tid) - 1ull));
            if (mv && pos >= s0 && pos < s0 + 256) widx[pos - s0] = ch + tid;
            base += (int)__popcll(bal);
        }
        if (tid == 0) {
            cntS = base;
            if (x == 0 && h == 0 && w == 0) meta[bb] = base;
        }
    }
    __syncthreads();

    int  cnt   = cntS;
    int  c     = s0 + tid;
    bool valid = c < cnt;
    int  gs    = valid ? widx[tid] : 0;

    // (1/sqrt5)*log2(e)*128 — x128 makes the MFMA emit Schraudolph's 128*x directly
    const float QSC = 0.44721359549995793f * 1.4426950408889634f * 128.0f;
    const float* base = (x == 0) ? q : ((x == 1) ? k : v);

    float xq[DIM], xg[DIM];
    {
        const float4* r4 = (const float4*)(base + (size_t)(bb * SEQ + c) * DIM);
        const float4* g4 = (const float4*)(base + (size_t)(bb * SEQ + gs) * DIM);
        #pragma unroll
        for (int i = 0; i < 5; ++i) {
            float4 a = r4[i], g = g4[i];
            xq[i*4+0]=a.x; xq[i*4+1]=a.y; xq[i*4+2]=a.z; xq[i*4+3]=a.w;
            xg[i*4+0]=g.x; xg[i*4+1]=g.y; xg[i*4+2]=g.z; xg[i*4+3]=g.w;
        }
    }

    #define DOT20(xv, t, j, dst) {                                        \
        float acc_ = bsh[t][j];                                           \
        const float4* wr_ = (const float4*)&Ws[t][(j) * DIM];             \
        _Pragma("unroll")                                                 \
        for (int i4 = 0; i4 < 5; ++i4) {                                  \
            float4 w_ = wr_[i4];                                          \
            acc_ += (xv)[i4*4+0]*w_.x + (xv)[i4*4+1]*w_.y                 \
                  + (xv)[i4*4+2]*w_.z + (xv)[i4*4+3]*w_.w;                \
        }                                                                 \
        dst = acc_;                                                       \
    }

    size_t row = ((size_t)(x * B + bb) * H + h) * SEQ + c;

    // Q-role (W0): pre-scaled (incl. x128), hi/lo bf16 split; hi[5]=128 (bias), lo[5]=0
    short8 qhi = {0, 0, 0, 0, 0, B128, 0, 0};
    short8 qlo = {0, 0, 0, 0, 0, 0, 0, 0};
    #pragma unroll
    for (int d = 0; d < DKN; ++d) {
        float y; DOT20(xq, 0, h * DKN + d, y);
        y *= QSC;
        unsigned short hb = bf16b(y);
        qhi[d] = (short)hb;
        qlo[d] = (short)bf16b(y - bf16f(hb));
    }
    ((short8*)Qt)[row * 2 + 0] = qhi;
    ((short8*)Qt)[row * 2 + 1] = qlo;

    // K-role (W1) on gathered key row, or sentinel:
    // sentinel K = [0,0,0,0,0,-126,0,0] -> t = 16250 - 126*128 = 122 -> P bits ~ 0
    short8 rk = {0, 0, 0, 0, 0, valid ? (short)0 : SENTB, 0, 0};
    if (valid) {
        #pragma unroll
        for (int d = 0; d < DKN; ++d) {
            float y; DOT20(xg, 1, h * DKN + d, y);
            rk[d] = (short)bf16b(y);
        }
    }
    ((short8*)Kt)[row] = rk;

    // V-role (W2): transposed store at sig32-permuted column; row5 = 1 (l-col)
    if (valid) {
        size_t vb = ((size_t)(x * B + bb) * H + h) * 8 * SEQ;
        int vcol = (c & ~31) + sig32(c & 31);
        #pragma unroll
        for (int d = 0; d < DKN; ++d) {
            float y; DOT20(xg, 2, h * DKN + d, y);
            Vt[vb + (size_t)d * SEQ + vcol] = (short)bf16b(y);
        }
        Vt[vb + (size_t)5 * SEQ + vcol] = ONEB;
    }
}

// ---------------- barrier-free MFMA flash attention (32x32x16 S^T form) ----------------
// 2 waves/block; 2 q-tiles interleaved, 64-key unrolled k-loop.
// Score MFMA C-init = PBIASM -> D's low16 bits ARE bf16(2^score). P-gen = 1 perm/pair.
__global__ __launch_bounds__(128) void attn_kernel(
    const short* __restrict__ Qt, const short* __restrict__ Kt,
    const short* __restrict__ Vt, const int* __restrict__ meta,
    float* __restrict__ pre)
{
    int lane = threadIdx.x & 63;
    int l31  = lane & 31, half = lane >> 5;

    int lin = blockIdx.x * 2 + (threadIdx.x >> 6);   // 3072*2 = 6144 waves
    int qt  = lin & 31; lin >>= 5;
    int h   = lin & 3;  lin >>= 2;
    int b   = lin & 7;  lin >>= 3;
    int p   = lin;
    int a   = (0x212010 >> (4 * p)) & 0xF;   // Q source
    int kv  = (0x120201 >> (4 * p)) & 0xF;   // K/V source

    int cnt  = meta[b];
    int kend = (cnt + 63) & ~63;             // 64-aligned; sentinel K rows pad

    const short*  Qb = Qt + ((size_t)(a  * B + b) * H + h) * SEQ * 16;
    const short8* Kb = (const short8*)Kt + ((size_t)(kv * B + b) * H + h) * SEQ;
    const short*  Vb = Vt + ((size_t)(kv * B + b) * H + h) * 8 * SEQ;
    const short*  Vr = Vb + (size_t)(l31 & 7) * SEQ + half * 8;

    int qb0 = qt * 32, qb1 = qt * 32 + 1024;
    // B-frag Q: B[n=q=l31][k=half*8+j]; half0 = Q-hi (k0-7), half1 = Q-lo (k8-15)
    short8 qf0 = *(const short8*)(Qb + (size_t)(qb0 + l31) * 16 + half * 8);
    short8 qf1 = *(const short8*)(Qb + (size_t)(qb1 + l31) * 16 + half * 8);

    f32x16 zc = {0.f,0.f,0.f,0.f,0.f,0.f,0.f,0.f,0.f,0.f,0.f,0.f,0.f,0.f,0.f,0.f};
    f32x16 sb = {PBIASM,PBIASM,PBIASM,PBIASM,PBIASM,PBIASM,PBIASM,PBIASM,
                 PBIASM,PBIASM,PBIASM,PBIASM,PBIASM,PBIASM,PBIASM,PBIASM};
    f32x16 acc0 = zc, acc1 = zc;

    // prefetch iteration 0 (64 keys: sub-steps A and B)
    short8 kfA = Kb[l31],      kfB = Kb[32 + l31];
    short8 vaA = *(const short8*)(Vr);
    short8 vcA = *(const short8*)(Vr + 16);
    short8 vaB = *(const short8*)(Vr + 32);
    short8 vcB = *(const short8*)(Vr + 48);

    for (int c0 = 0; c0 < kend; c0 += 64) {
        int c1 = c0 + 64;   // final prefetch reads stray in-ws bytes, never consumed
        short8 kfA_n = Kb[c1 + l31];
        short8 kfB_n = Kb[c1 + 32 + l31];
        short8 vaA_n = *(const short8*)(Vr + c1);
        short8 vcA_n = *(const short8*)(Vr + c1 + 16);
        short8 vaB_n = *(const short8*)(Vr + c1 + 32);
        short8 vcB_n = *(const short8*)(Vr + c1 + 48);

        // S^T + magic: D = MAGIC + 128*score + bias; col=q=l31, key=(reg&3)+8*(reg>>2)+4*half
        f32x16 dA0 = __builtin_amdgcn_mfma_f32_32x32x16_bf16(kfA, qf0, sb, 0, 0, 0);
        f32x16 dA1 = __builtin_amdgcn_mfma_f32_32x32x16_bf16(kfA, qf1, sb, 0, 0, 0);
        f32x16 dB0 = __builtin_amdgcn_mfma_f32_32x32x16_bf16(kfB, qf0, sb, 0, 0, 0);
        f32x16 dB1 = __builtin_amdgcn_mfma_f32_32x32x16_bf16(kfB, qf1, sb, 0, 0, 0);

        // P-gen: ONE v_perm per pair — no exp, no cvt, no max.
        unsigned pA00[4], pA01[4], pA10[4], pA11[4];
        unsigned pB00[4], pB01[4], pB10[4], pB11[4];
        #pragma unroll
        for (int r = 0; r < 4; ++r) {
            pA00[r] = pk_pbits(dA0[2 * r], dA0[2 * r + 1]);
            pA01[r] = pk_pbits(dA0[2 * r + 8], dA0[2 * r + 9]);
            pA10[r] = pk_pbits(dA1[2 * r], dA1[2 * r + 1]);
            pA11[r] = pk_pbits(dA1[2 * r + 8], dA1[2 * r + 9]);
            pB00[r] = pk_pbits(dB0[2 * r], dB0[2 * r + 1]);
            pB01[r] = pk_pbits(dB0[2 * r + 8], dB0[2 * r + 9]);
            pB10[r] = pk_pbits(dB1[2 * r], dB1[2 * r + 1]);
            pB11[r] = pk_pbits(dB1[2 * r + 8], dB1[2 * r + 9]);
        }
        short8 fA00, fA01, fA10, fA11, fB00, fB01, fB10, fB11;
        __builtin_memcpy(&fA00, pA00, 16); __builtin_memcpy(&fA01, pA01, 16);
        __builtin_memcpy(&fA10, pA10, 16); __builtin_memcpy(&fA11, pA11, 16);
        __builtin_memcpy(&fB00, pB00, 16); __builtin_memcpy(&fB01, pB01, 16);
        __builtin_memcpy(&fB10, pB10, 16); __builtin_memcpy(&fB11, pB11, 16);

        // O^T: A=V^T[m=dim][k-slot], B=P[n=q][k-slot]; Vt row5=1 -> row5 of D = l
        acc0 = __builtin_amdgcn_mfma_f32_32x32x16_bf16(vaA, fA00, acc0, 0, 0, 0);
        acc1 = __builtin_amdgcn_mfma_f32_32x32x16_bf16(vaA, fA10, acc1, 0, 0, 0);
        acc0 = __builtin_amdgcn_mfma_f32_32x32x16_bf16(vcA, fA01, acc0, 0, 0, 0);
        acc1 = __builtin_amdgcn_mfma_f32_32x32x16_bf16(vcA, fA11, acc1, 0, 0, 0);
        acc0 = __builtin_amdgcn_mfma_f32_32x32x16_bf16(vaB, fB00, acc0, 0, 0, 0);
        acc1 = __builtin_amdgcn_mfma_f32_32x32x16_bf16(vaB, fB10, acc1, 0, 0, 0);
        acc0 = __builtin_amdgcn_mfma_f32_32x32x16_bf16(vcB, fB01, acc0, 0, 0, 0);
        acc1 = __builtin_amdgcn_mfma_f32_32x32x16_bf16(vcB, fB11, acc1, 0, 0, 0);

        kfA = kfA_n; kfB = kfB_n;
        vaA = vaA_n; vcA = vcA_n; vaB = vaB_n; vcB = vcB_n;
    }

    // D rows: dim0-3 = half0 regs 0-3; dim4 = half1 reg0; l (row5) = half1 reg1
    float* base0 = pre + (((size_t)p * B + b) * H + h) * SEQ * PRE8;
    {
        float lv  = __shfl(acc0[1], 32 + l31, 64);
        float inv = 1.0f / lv;
        float* dst = base0 + (size_t)(qb0 + l31) * PRE8;
        if (half == 0)
            *(float4*)dst = make_float4(acc0[0]*inv, acc0[1]*inv, acc0[2]*inv, acc0[3]*inv);
        else
            dst[4] = acc0[0] * inv;
    }
    {
        float lv  = __shfl(acc1[1], 32 + l31, 64);
        float inv = 1.0f / lv;
        float* dst = base0 + (size_t)(qb1 + l31) * PRE8;
        if (half == 0)
            *(float4*)dst = make_float4(acc1[0]*inv, acc1[1]*inv, acc1[2]*inv, acc1[3]*inv);
        else
            dst[4] = acc1[0] * inv;
    }
}

// ---------------- sum 6 pairs + output projection ----------------
__global__ __launch_bounds__(256) void final_kernel(
    const float* __restrict__ pre,
    const float* __restrict__ W3, const float* __restrict__ b3,
    float* __restrict__ out)
{
    __shared__ float Ws[DIM * DIM];
    __shared__ float bs[DIM];
    int tid = threadIdx.x;
    for (int i = tid; i < DIM * DIM; i += 256) Ws[i] = W3[i];
    if (tid < DIM) bs[tid] = b3[tid];
    __syncthreads();

    int g = blockIdx.x * 256 + tid;      // B*SEQ = 16384 exactly
    int b = g / SEQ;
    int s = g - b * SEQ;

    float x[DIM];
    #pragma unroll
    for (int i = 0; i < DIM; ++i) x[i] = 0.f;

    for (int p = 0; p < 6; ++p) {
        #pragma unroll
        for (int h = 0; h < H; ++h) {
            const float* sr = pre + (((size_t)p * B + b) * H + h) * SEQ * PRE8
                                  + (size_t)s * PRE8;
            float4 a = *(const float4*)sr;
            float  a4 = sr[4];
            x[h * DKN + 0] += a.x; x[h * DKN + 1] += a.y; x[h * DKN + 2] += a.z;
            x[h * DKN + 3] += a.w; x[h * DKN + 4] += a4;
        }
    }

    float y[DIM];
    for (int j = 0; j < DIM; ++j) {
        float acc = bs[j];
        const float4* wr = (const float4*)&Ws[j * DIM];
        #pragma unroll
        for (int i4 = 0; i4 < 5; ++i4) {
            float4 w = wr[i4];
            acc += x[i4*4+0]*w.x + x[i4*4+1]*w.y + x[i4*4+2]*w.z + x[i4*4+3]*w.w;
        }
        y[j] = acc;
    }
    float4* dst = (float4*)(out + (size_t)(b * SEQ + s) * DIM);
    #pragma unroll
    for (int j4 = 0; j4 < 5; ++j4)
        dst[j4] = make_float4(y[j4*4+0], y[j4*4+1], y[j4*4+2], y[j4*4+3]);
}

extern "C" void kernel_launch(void* const* d_in, const int* in_sizes, int n_in,
                              void* d_out, int out_size, void* d_ws, size_t ws_size,
                              hipStream_t stream) {
    const float* q    = (const float*)d_in[0];
    const float* k    = (const float*)d_in[1];
    const float* v    = (const float*)d_in[2];
    const int*   mask = (const int*)d_in[3];
    const float* W0 = (const float*)d_in[4];  const float* b0 = (const float*)d_in[5];
    const float* W1 = (const float*)d_in[6];  const float* b1 = (const float*)d_in[7];
    const float* W2 = (const float*)d_in[8];  const float* b2 = (const float*)d_in[9];
    const float* W3 = (const float*)d_in[10]; const float* b3 = (const float*)d_in[11];

    const size_t NROW = (size_t)3 * B * H * SEQ;       // 196608
    short* Qt = (short*)d_ws;                          // NROW*16 shorts (6 MB)
    short* Kt = Qt + NROW * 16;                        // NROW*8 shorts  (3 MB)
    short* Vt = Kt + NROW * 8;                         // NROW*8 shorts  (3 MB)
    float* pre = (float*)(Vt + NROW * 8);              // 6*B*H*SEQ*8 floats (12.6 MB)
    int*   meta = (int*)(pre + (size_t)6 * B * H * SEQ * PRE8);
    float* out = (float*)d_out;

    proj_kernel<<<dim3(3 * B * H * (SEQ / 256)), dim3(256), 0, stream>>>(
        q, k, v, W0, b0, W1, b1, W2, b2, mask, Qt, Kt, Vt, meta);
    attn_kernel<<<dim3(6 * B * H * 32 / 2), dim3(128), 0, stream>>>(
        Qt, Kt, Vt, meta, pre);
    final_kernel<<<dim3(B * SEQ / 256), dim3(256), 0, stream>>>(pre, W3, b3, out);
}

// Round 17
// 157.857 us; speedup vs baseline: 1.1258x; 1.0281x over previous
//
#include <hip/hip_runtime.h>
#include <cstdint>
#include <cstddef>

#define B    8
#define SEQ  2048
#define H    4
#define DKN  5
#define DIM  20
#define PRE8 8
#define SENTB ((short)0xC2FC) // bf16(-126): sentinel bias product -> t=122 -> P bits ~ 0
#define ONEB  ((short)0x3F80) // bf16(1.0)
#define B128  ((short)0x4300) // bf16(128.0) - Q bias slot (x128 folded into scores)
// MAGIC (2^23 sticky-int) + Schraudolph bias (127*128 - minimax shift).
// D = MAGIC + 128*score + 16250 stays in [2^23,2^24): low16 bits of D ARE bf16(2^score).
#define PBIASM 12599162.0f

typedef short short8 __attribute__((ext_vector_type(8)));
typedef float f32x16 __attribute__((ext_vector_type(16)));

static __device__ __forceinline__ unsigned short bf16b(float x) {
    union { float f; unsigned u; } v; v.f = x;
    unsigned r = v.u + 0x7FFFu + ((v.u >> 16) & 1u);   // RTNE
    return (unsigned short)(r >> 16);
}
static __device__ __forceinline__ float bf16f(unsigned short h) {
    union { unsigned u; float f; } v; v.u = ((unsigned)h) << 16;
    return v.f;
}
// P-gen = ONE v_perm per pair: D-reg low16 bits are already the bf16 P value.
static __device__ __forceinline__ unsigned pk_pbits(float ta, float tb) {
    unsigned ia, ib;
    __builtin_memcpy(&ia, &ta, 4);
    __builtin_memcpy(&ib, &tb, 4);
    return __builtin_amdgcn_perm(ib, ia, 0x05040100u);  // {lo16(ib), lo16(ia)}
}
// key offset t (0..31) -> Vt physical column slot (32x32x16 PV k-slot inverse)
static __device__ __forceinline__ int sig32(int t) {
    return (t & 19) | ((t & 4) << 1) | ((t & 8) >> 1);
}

// ws layout:
//   Qt : short [x][b][h][s][16]   hi(0..7, [5]=128 bias) | lo(8..15, [5]=0)  6 MB
//   Kt : short [x][b][h][c][8]    compacted keys; c>=cnt sentinel            3 MB
//   Vt : short [x][b][h][8][SEQ]  transposed values at sig32 columns; r5=1   3 MB
//   pre : float [p][b][h][s][8]                                             12.6 MB
//   meta: int [B]

// ---------------- projections + in-block windowed compaction ----------------
__global__ __launch_bounds__(256) void proj_kernel(
    const float* __restrict__ q, const float* __restrict__ k, const float* __restrict__ v,
    const float* __restrict__ W0, const float* __restrict__ b0,
    const float* __restrict__ W1, const float* __restrict__ b1,
    const float* __restrict__ W2, const float* __restrict__ b2,
    const int* __restrict__ mask,
    short* __restrict__ Qt, short* __restrict__ Kt, short* __restrict__ Vt,
    int* __restrict__ meta)
{
    __shared__ float Ws[3][DIM * DIM];
    __shared__ float bsh[3][DIM];
    __shared__ int   widx[256];
    __shared__ int   cntS;

    int tid = threadIdx.x;
    int blk = blockIdx.x;            // 3*8*4*8 = 768
    int w   = blk & 7;  blk >>= 3;   // s-window
    int h   = blk & 3;  blk >>= 2;
    int bb  = blk & 7;  blk >>= 3;
    int x   = blk;                   // 0..2
    int s0  = w * 256;

    for (int i = tid; i < DIM * DIM; i += 256) {
        Ws[0][i] = W0[i]; Ws[1][i] = W1[i]; Ws[2][i] = W2[i];
    }
    if (tid < DIM) { bsh[0][tid] = b0[tid]; bsh[1][tid] = b1[tid]; bsh[2][tid] = b2[tid]; }

    // wave 0: scan mask[bb], record gather indices for compacted window [s0,s0+256)
    if (tid < 64) {
        const int* mrow = mask + bb * SEQ;
        int base = 0;
        for (int ch = 0; ch < SEQ; ch += 64) {
            int mv = mrow[ch + tid];
            unsigned long long bal = __ballot(mv != 0);
            int pos = base + (int)__popcll(bal & ((1ull << tid) - 1ull));
            if (mv && pos >= s0 && pos < s0 + 256) widx[pos - s0] = ch + tid;
            base += (int)__popcll(bal);
        }
        if (tid == 0) {
            cntS = base;
            if (x == 0 && h == 0 && w == 0) meta[bb] = base;
        }
    }
    __syncthreads();

    int  cnt   = cntS;
    int  c     = s0 + tid;
    bool valid = c < cnt;
    int  gs    = valid ? widx[tid] : 0;

    // (1/sqrt5)*log2(e)*128 — x128 makes the MFMA emit Schraudolph's 128*x directly
    const float QSC = 0.44721359549995793f * 1.4426950408889634f * 128.0f;
    const float* base = (x == 0) ? q : ((x == 1) ? k : v);

    float xq[DIM], xg[DIM];
    {
        const float4* r4 = (const float4*)(base + (size_t)(bb * SEQ + c) * DIM);
        const float4* g4 = (const float4*)(base + (size_t)(bb * SEQ + gs) * DIM);
        #pragma unroll
        for (int i = 0; i < 5; ++i) {
            float4 a = r4[i], g = g4[i];
            xq[i*4+0]=a.x; xq[i*4+1]=a.y; xq[i*4+2]=a.z; xq[i*4+3]=a.w;
            xg[i*4+0]=g.x; xg[i*4+1]=g.y; xg[i*4+2]=g.z; xg[i*4+3]=g.w;
        }
    }

    #define DOT20(xv, t, j, dst) {                                        \
        float acc_ = bsh[t][j];                                           \
        const float4* wr_ = (const float4*)&Ws[t][(j) * DIM];             \
        _Pragma("unroll")                                                 \
        for (int i4 = 0; i4 < 5; ++i4) {                                  \
            float4 w_ = wr_[i4];                                          \
            acc_ += (xv)[i4*4+0]*w_.x + (xv)[i4*4+1]*w_.y                 \
                  + (xv)[i4*4+2]*w_.z + (xv)[i4*4+3]*w_.w;                \
        }                                                                 \
        dst = acc_;                                                       \
    }

    size_t row = ((size_t)(x * B + bb) * H + h) * SEQ + c;

    // Q-role (W0): pre-scaled (incl. x128), hi/lo bf16 split; hi[5]=128 (bias), lo[5]=0
    short8 qhi = {0, 0, 0, 0, 0, B128, 0, 0};
    short8 qlo = {0, 0, 0, 0, 0, 0, 0, 0};
    #pragma unroll
    for (int d = 0; d < DKN; ++d) {
        float y; DOT20(xq, 0, h * DKN + d, y);
        y *= QSC;
        unsigned short hb = bf16b(y);
        qhi[d] = (short)hb;
        qlo[d] = (short)bf16b(y - bf16f(hb));
    }
    ((short8*)Qt)[row * 2 + 0] = qhi;
    ((short8*)Qt)[row * 2 + 1] = qlo;

    // K-role (W1) on gathered key row, or sentinel:
    // sentinel K = [0,0,0,0,0,-126,0,0] -> t = 16250 - 126*128 = 122 -> P bits ~ 0
    short8 rk = {0, 0, 0, 0, 0, valid ? (short)0 : SENTB, 0, 0};
    if (valid) {
        #pragma unroll
        for (int d = 0; d < DKN; ++d) {
            float y; DOT20(xg, 1, h * DKN + d, y);
            rk[d] = (short)bf16b(y);
        }
    }
    ((short8*)Kt)[row] = rk;

    // V-role (W2): transposed store at sig32-permuted column; row5 = 1 (l-col)
    if (valid) {
        size_t vb = ((size_t)(x * B + bb) * H + h) * 8 * SEQ;
        int vcol = (c & ~31) + sig32(c & 31);
        #pragma unroll
        for (int d = 0; d < DKN; ++d) {
            float y; DOT20(xg, 2, h * DKN + d, y);
            Vt[vb + (size_t)d * SEQ + vcol] = (short)bf16b(y);
        }
        Vt[vb + (size_t)5 * SEQ + vcol] = ONEB;
    }
}

// ---------------- barrier-free MFMA flash attention (32x32x16 S^T form) ----------------
// 2 waves/block; each wave: 4 q-tiles interleaved in one shared 64-key k-loop
// (K/V loaded once per 128 q-rows — halves L2/L3 traffic vs 2-tile).
__global__ __launch_bounds__(128) void attn_kernel(
    const short* __restrict__ Qt, const short* __restrict__ Kt,
    const short* __restrict__ Vt, const int* __restrict__ meta,
    float* __restrict__ pre)
{
    int lane = threadIdx.x & 63;
    int l31  = lane & 31, half = lane >> 5;

    int lin = blockIdx.x * 2 + (threadIdx.x >> 6);   // 1536*2 = 3072 waves
    int qt  = lin & 15; lin >>= 4;
    int h   = lin & 3;  lin >>= 2;
    int b   = lin & 7;  lin >>= 3;
    int p   = lin;
    int a   = (0x212010 >> (4 * p)) & 0xF;   // Q source
    int kv  = (0x120201 >> (4 * p)) & 0xF;   // K/V source

    int cnt  = meta[b];
    int kend = (cnt + 63) & ~63;             // 64-aligned; sentinel K rows pad

    const short*  Qb = Qt + ((size_t)(a  * B + b) * H + h) * SEQ * 16;
    const short8* Kb = (const short8*)Kt + ((size_t)(kv * B + b) * H + h) * SEQ;
    const short*  Vb = Vt + ((size_t)(kv * B + b) * H + h) * 8 * SEQ;
    const short*  Vr = Vb + (size_t)(l31 & 7) * SEQ + half * 8;

    // 4 q-tiles per wave: qbase = qt*32 + t*512
    // B-frag Q: B[n=q=l31][k=half*8+j]; half0 = Q-hi (k0-7), half1 = Q-lo (k8-15)
    short8 qf[4];
    f32x16 acc[4];
    f32x16 zc = {0.f,0.f,0.f,0.f,0.f,0.f,0.f,0.f,0.f,0.f,0.f,0.f,0.f,0.f,0.f,0.f};
    f32x16 sb = {PBIASM,PBIASM,PBIASM,PBIASM,PBIASM,PBIASM,PBIASM,PBIASM,
                 PBIASM,PBIASM,PBIASM,PBIASM,PBIASM,PBIASM,PBIASM,PBIASM};
    #pragma unroll
    for (int t = 0; t < 4; ++t) {
        int qb = qt * 32 + t * 512;
        qf[t]  = *(const short8*)(Qb + (size_t)(qb + l31) * 16 + half * 8);
        acc[t] = zc;
    }

    // prefetch iteration 0 (64 keys: sub-steps A and B)
    short8 kfA = Kb[l31],      kfB = Kb[32 + l31];
    short8 vaA = *(const short8*)(Vr);
    short8 vcA = *(const short8*)(Vr + 16);
    short8 vaB = *(const short8*)(Vr + 32);
    short8 vcB = *(const short8*)(Vr + 48);

    for (int c0 = 0; c0 < kend; c0 += 64) {
        int c1 = c0 + 64;   // final prefetch reads stray in-ws bytes, never consumed
        short8 kfA_n = Kb[c1 + l31];
        short8 kfB_n = Kb[c1 + 32 + l31];
        short8 vaA_n = *(const short8*)(Vr + c1);
        short8 vcA_n = *(const short8*)(Vr + c1 + 16);
        short8 vaB_n = *(const short8*)(Vr + c1 + 32);
        short8 vcB_n = *(const short8*)(Vr + c1 + 48);

        // 4 independent q-tile chains; d consumed immediately (low liveness)
        #pragma unroll
        for (int t = 0; t < 4; ++t) {
            // S^T + magic: D = MAGIC + 128*score + bias; col=q, key=(reg&3)+8*(reg>>2)+4*half
            f32x16 dA = __builtin_amdgcn_mfma_f32_32x32x16_bf16(kfA, qf[t], sb, 0, 0, 0);
            unsigned p0[4], p1[4];
            #pragma unroll
            for (int r = 0; r < 4; ++r) {
                p0[r] = pk_pbits(dA[2 * r],     dA[2 * r + 1]);
                p1[r] = pk_pbits(dA[2 * r + 8], dA[2 * r + 9]);
            }
            short8 f0, f1;
            __builtin_memcpy(&f0, p0, 16);
            __builtin_memcpy(&f1, p1, 16);
            acc[t] = __builtin_amdgcn_mfma_f32_32x32x16_bf16(vaA, f0, acc[t], 0, 0, 0);
            acc[t] = __builtin_amdgcn_mfma_f32_32x32x16_bf16(vcA, f1, acc[t], 0, 0, 0);

            f32x16 dB = __builtin_amdgcn_mfma_f32_32x32x16_bf16(kfB, qf[t], sb, 0, 0, 0);
            #pragma unroll
            for (int r = 0; r < 4; ++r) {
                p0[r] = pk_pbits(dB[2 * r],     dB[2 * r + 1]);
                p1[r] = pk_pbits(dB[2 * r + 8], dB[2 * r + 9]);
            }
            __builtin_memcpy(&f0, p0, 16);
            __builtin_memcpy(&f1, p1, 16);
            acc[t] = __builtin_amdgcn_mfma_f32_32x32x16_bf16(vaB, f0, acc[t], 0, 0, 0);
            acc[t] = __builtin_amdgcn_mfma_f32_32x32x16_bf16(vcB, f1, acc[t], 0, 0, 0);
        }

        kfA = kfA_n; kfB = kfB_n;
        vaA = vaA_n; vcA = vcA_n; vaB = vaB_n; vcB = vcB_n;
    }

    // D rows: dim0-3 = half0 regs 0-3; dim4 = half1 reg0; l (row5) = half1 reg1
    float* base0 = pre + (((size_t)p * B + b) * H + h) * SEQ * PRE8;
    #pragma unroll
    for (int t = 0; t < 4; ++t) {
        int qb = qt * 32 + t * 512;
        float lv  = __shfl(acc[t][1], 32 + l31, 64);
        float inv = 1.0f / lv;
        float* dst = base0 + (size_t)(qb + l31) * PRE8;
        if (half == 0)
            *(float4*)dst = make_float4(acc[t][0]*inv, acc[t][1]*inv,
                                        acc[t][2]*inv, acc[t][3]*inv);
        else
            dst[4] = acc[t][0] * inv;
    }
}

// ---------------- sum 6 pairs + output projection ----------------
__global__ __launch_bounds__(256) void final_kernel(
    const float* __restrict__ pre,
    const float* __restrict__ W3, const float* __restrict__ b3,
    float* __restrict__ out)
{
    __shared__ float Ws[DIM * DIM];
    __shared__ float bs[DIM];
    int tid = threadIdx.x;
    for (int i = tid; i < DIM * DIM; i += 256) Ws[i] = W3[i];
    if (tid < DIM) bs[tid] = b3[tid];
    __syncthreads();

    int g = blockIdx.x * 256 + tid;      // B*SEQ = 16384 exactly
    int b = g / SEQ;
    int s = g - b * SEQ;

    float x[DIM];
    #pragma unroll
    for (int i = 0; i < DIM; ++i) x[i] = 0.f;

    for (int p = 0; p < 6; ++p) {
        #pragma unroll
        for (int h = 0; h < H; ++h) {
            const float* sr = pre + (((size_t)p * B + b) * H + h) * SEQ * PRE8
                                  + (size_t)s * PRE8;
            float4 a = *(const float4*)sr;
            float  a4 = sr[4];
            x[h * DKN + 0] += a.x; x[h * DKN + 1] += a.y; x[h * DKN + 2] += a.z;
            x[h * DKN + 3] += a.w; x[h * DKN + 4] += a4;
        }
    }

    float y[DIM];
    for (int j = 0; j < DIM; ++j) {
        float acc = bs[j];
        const float4* wr = (const float4*)&Ws[j * DIM];
        #pragma unroll
        for (int i4 = 0; i4 < 5; ++i4) {
            float4 w = wr[i4];
            acc += x[i4*4+0]*w.x + x[i4*4+1]*w.y + x[i4*4+2]*w.z + x[i4*4+3]*w.w;
        }
        y[j] = acc;
    }
    float4* dst = (float4*)(out + (size_t)(b * SEQ + s) * DIM);
    #pragma unroll
    for (int j4 = 0; j4 < 5; ++j4)
        dst[j4] = make_float4(y[j4*4+0], y[j4*4+1], y[j4*4+2], y[j4*4+3]);
}

extern "C" void kernel_launch(void* const* d_in, const int* in_sizes, int n_in,
                              void* d_out, int out_size, void* d_ws, size_t ws_size,
                              hipStream_t stream) {
    const float* q    = (const float*)d_in[0];
    const float* k    = (const float*)d_in[1];
    const float* v    = (const float*)d_in[2];
    const int*   mask = (const int*)d_in[3];
    const float* W0 = (const float*)d_in[4];  const float* b0 = (const float*)d_in[5];
    const float* W1 = (const float*)d_in[6];  const float* b1 = (const float*)d_in[7];
    const float* W2 = (const float*)d_in[8];  const float* b2 = (const float*)d_in[9];
    const float* W3 = (const float*)d_in[10]; const float* b3 = (const float*)d_in[11];

    const size_t NROW = (size_t)3 * B * H * SEQ;       // 196608
    short* Qt = (short*)d_ws;                          // NROW*16 shorts (6 MB)
    short* Kt = Qt + NROW * 16;                        // NROW*8 shorts  (3 MB)
    short* Vt = Kt + NROW * 8;                         // NROW*8 shorts  (3 MB)
    float* pre = (float*)(Vt + NROW * 8);              // 6*B*H*SEQ*8 floats (12.6 MB)
    int*   meta = (int*)(pre + (size_t)6 * B * H * SEQ * PRE8);
    float* out = (float*)d_out;

    proj_kernel<<<dim3(3 * B * H * (SEQ / 256)), dim3(256), 0, stream>>>(
        q, k, v, W0, b0, W1, b1, W2, b2, mask, Qt, Kt, Vt, meta);
    attn_kernel<<<dim3(6 * B * H * 16 / 2), dim3(128), 0, stream>>>(
        Qt, Kt, Vt, meta, pre);
    final_kernel<<<dim3(B * SEQ / 256), dim3(256), 0, stream>>>(pre, W3, b3, out);
}

// Round 18
// 149.551 us; speedup vs baseline: 1.1883x; 1.0555x over previous
//
#include <hip/hip_runtime.h>
#include <cstdint>
#include <cstddef>

#define B    8
#define SEQ  2048
#define H    4
#define DKN  5
#define DIM  20
#define PRE8 8
#define SENTB ((short)0xC2FC) // bf16(-126): sentinel bias product -> t=122 -> P bits ~ 0
#define ONEB  ((short)0x3F80) // bf16(1.0)
#define B128  ((short)0x4300) // bf16(128.0) - Q bias slot (x128 folded into scores)
// MAGIC (2^23 sticky-int) + Schraudolph bias (127*128 - minimax shift).
// D = MAGIC + 128*score + 16250 stays in [2^23,2^24): low16 bits of D ARE bf16(2^score).
#define PBIASM 12599162.0f

typedef short short8 __attribute__((ext_vector_type(8)));
typedef float f32x16 __attribute__((ext_vector_type(16)));

static __device__ __forceinline__ unsigned short bf16b(float x) {
    union { float f; unsigned u; } v; v.f = x;
    unsigned r = v.u + 0x7FFFu + ((v.u >> 16) & 1u);   // RTNE
    return (unsigned short)(r >> 16);
}
static __device__ __forceinline__ float bf16f(unsigned short h) {
    union { unsigned u; float f; } v; v.u = ((unsigned)h) << 16;
    return v.f;
}
// P-gen = ONE v_perm per pair: D-reg low16 bits are already the bf16 P value.
static __device__ __forceinline__ unsigned pk_pbits(float ta, float tb) {
    unsigned ia, ib;
    __builtin_memcpy(&ia, &ta, 4);
    __builtin_memcpy(&ib, &tb, 4);
    return __builtin_amdgcn_perm(ib, ia, 0x05040100u);  // {lo16(ib), lo16(ia)}
}
// key offset t (0..31) -> Vt physical column slot (32x32x16 PV k-slot inverse)
static __device__ __forceinline__ int sig32(int t) {
    return (t & 19) | ((t & 4) << 1) | ((t & 8) >> 1);
}

// ws layout:
//   Qt : short [x][b][h][s][16]   hi(0..7, [5]=128 bias) | lo(8..15, [5]=0)  6 MB
//   Kt : short [x][b][h][c][8]    compacted keys; c>=cnt sentinel            3 MB
//   Vt : short [x][b][h][8][SEQ]  transposed values at sig32 columns; r5=1   3 MB
//   pre : float [p][b][h][s][8]                                             12.6 MB
//   meta: int [B]

// ---------------- projections + in-block windowed compaction ----------------
__global__ __launch_bounds__(256) void proj_kernel(
    const float* __restrict__ q, const float* __restrict__ k, const float* __restrict__ v,
    const float* __restrict__ W0, const float* __restrict__ b0,
    const float* __restrict__ W1, const float* __restrict__ b1,
    const float* __restrict__ W2, const float* __restrict__ b2,
    const int* __restrict__ mask,
    short* __restrict__ Qt, short* __restrict__ Kt, short* __restrict__ Vt,
    int* __restrict__ meta)
{
    __shared__ float Ws[3][DIM * DIM];
    __shared__ float bsh[3][DIM];
    __shared__ int   widx[256];
    __shared__ int   cntS;

    int tid = threadIdx.x;
    int blk = blockIdx.x;            // 3*8*4*8 = 768
    int w   = blk & 7;  blk >>= 3;   // s-window
    int h   = blk & 3;  blk >>= 2;
    int bb  = blk & 7;  blk >>= 3;
    int x   = blk;                   // 0..2
    int s0  = w * 256;

    for (int i = tid; i < DIM * DIM; i += 256) {
        Ws[0][i] = W0[i]; Ws[1][i] = W1[i]; Ws[2][i] = W2[i];
    }
    if (tid < DIM) { bsh[0][tid] = b0[tid]; bsh[1][tid] = b1[tid]; bsh[2][tid] = b2[tid]; }

    // wave 0: scan mask[bb], record gather indices for compacted window [s0,s0+256)
    if (tid < 64) {
        const int* mrow = mask + bb * SEQ;
        int base = 0;
        for (int ch = 0; ch < SEQ; ch += 64) {
            int mv = mrow[ch + tid];
            unsigned long long bal = __ballot(mv != 0);
            int pos = base + (int)__popcll(bal & ((1ull << tid) - 1ull));
            if (mv && pos >= s0 && pos < s0 + 256) widx[pos - s0] = ch + tid;
            base += (int)__popcll(bal);
        }
        if (tid == 0) {
            cntS = base;
            if (x == 0 && h == 0 && w == 0) meta[bb] = base;
        }
    }
    __syncthreads();

    int  cnt   = cntS;
    int  c     = s0 + tid;
    bool valid = c < cnt;
    int  gs    = valid ? widx[tid] : 0;

    // (1/sqrt5)*log2(e)*128 — x128 makes the MFMA emit Schraudolph's 128*x directly
    const float QSC = 0.44721359549995793f * 1.4426950408889634f * 128.0f;
    const float* base = (x == 0) ? q : ((x == 1) ? k : v);

    float xq[DIM], xg[DIM];
    {
        const float4* r4 = (const float4*)(base + (size_t)(bb * SEQ + c) * DIM);
        const float4* g4 = (const float4*)(base + (size_t)(bb * SEQ + gs) * DIM);
        #pragma unroll
        for (int i = 0; i < 5; ++i) {
            float4 a = r4[i], g = g4[i];
            xq[i*4+0]=a.x; xq[i*4+1]=a.y; xq[i*4+2]=a.z; xq[i*4+3]=a.w;
            xg[i*4+0]=g.x; xg[i*4+1]=g.y; xg[i*4+2]=g.z; xg[i*4+3]=g.w;
        }
    }

    #define DOT20(xv, t, j, dst) {                                        \
        float acc_ = bsh[t][j];                                           \
        const float4* wr_ = (const float4*)&Ws[t][(j) * DIM];             \
        _Pragma("unroll")                                                 \
        for (int i4 = 0; i4 < 5; ++i4) {                                  \
            float4 w_ = wr_[i4];                                          \
            acc_ += (xv)[i4*4+0]*w_.x + (xv)[i4*4+1]*w_.y                 \
                  + (xv)[i4*4+2]*w_.z + (xv)[i4*4+3]*w_.w;                \
        }                                                                 \
        dst = acc_;                                                       \
    }

    size_t row = ((size_t)(x * B + bb) * H + h) * SEQ + c;

    // Q-role (W0): pre-scaled (incl. x128), hi/lo bf16 split; hi[5]=128 (bias), lo[5]=0
    short8 qhi = {0, 0, 0, 0, 0, B128, 0, 0};
    short8 qlo = {0, 0, 0, 0, 0, 0, 0, 0};
    #pragma unroll
    for (int d = 0; d < DKN; ++d) {
        float y; DOT20(xq, 0, h * DKN + d, y);
        y *= QSC;
        unsigned short hb = bf16b(y);
        qhi[d] = (short)hb;
        qlo[d] = (short)bf16b(y - bf16f(hb));
    }
    ((short8*)Qt)[row * 2 + 0] = qhi;
    ((short8*)Qt)[row * 2 + 1] = qlo;

    // K-role (W1) on gathered key row, or sentinel:
    // sentinel K = [0,0,0,0,0,-126,0,0] -> t = 16250 - 126*128 = 122 -> P bits ~ 0
    short8 rk = {0, 0, 0, 0, 0, valid ? (short)0 : SENTB, 0, 0};
    if (valid) {
        #pragma unroll
        for (int d = 0; d < DKN; ++d) {
            float y; DOT20(xg, 1, h * DKN + d, y);
            rk[d] = (short)bf16b(y);
        }
    }
    ((short8*)Kt)[row] = rk;

    // V-role (W2): transposed store at sig32-permuted column; row5 = 1 (l-col)
    if (valid) {
        size_t vb = ((size_t)(x * B + bb) * H + h) * 8 * SEQ;
        int vcol = (c & ~31) + sig32(c & 31);
        #pragma unroll
        for (int d = 0; d < DKN; ++d) {
            float y; DOT20(xg, 2, h * DKN + d, y);
            Vt[vb + (size_t)d * SEQ + vcol] = (short)bf16b(y);
        }
        Vt[vb + (size_t)5 * SEQ + vcol] = ONEB;
    }
}

// ---------------- barrier-free MFMA flash attention (32x32x16 S^T form) ----------------
// 2 waves/block, 4 q-tiles/wave, 64-key unrolled k-loop.
// R18: XCD-affine swizzle — blockIdx = qtpair*192 + group(p,b,h). Blocks sharing a
// K/V stream differ by 192 ≡ 0 (mod 8) -> same XCD under round-robin dispatch ->
// stream stays in that XCD's L2 (per-XCD set ~2.7 MB < 4 MB).
__global__ __launch_bounds__(128) void attn_kernel(
    const short* __restrict__ Qt, const short* __restrict__ Kt,
    const short* __restrict__ Vt, const int* __restrict__ meta,
    float* __restrict__ pre)
{
    int lane = threadIdx.x & 63;
    int l31  = lane & 31, half = lane >> 5;

    int wid  = blockIdx.x;            // 1536 = 8 qtpair * 192 group
    int qtp  = wid / 192;             // 0..7
    int grp  = wid - qtp * 192;       // (p,b,h)
    int qt   = qtp * 2 + (threadIdx.x >> 6);   // 0..15
    int h    = grp & 3;  grp >>= 2;
    int b    = grp & 7;  grp >>= 3;
    int p    = grp;                   // 0..5
    int a    = (0x212010 >> (4 * p)) & 0xF;   // Q source
    int kv   = (0x120201 >> (4 * p)) & 0xF;   // K/V source

    int cnt  = meta[b];
    int kend = (cnt + 63) & ~63;             // 64-aligned; sentinel K rows pad

    const short*  Qb = Qt + ((size_t)(a  * B + b) * H + h) * SEQ * 16;
    const short8* Kb = (const short8*)Kt + ((size_t)(kv * B + b) * H + h) * SEQ;
    const short*  Vb = Vt + ((size_t)(kv * B + b) * H + h) * 8 * SEQ;
    const short*  Vr = Vb + (size_t)(l31 & 7) * SEQ + half * 8;

    // 4 q-tiles per wave: qbase = qt*32 + t*512
    // B-frag Q: B[n=q=l31][k=half*8+j]; half0 = Q-hi (k0-7), half1 = Q-lo (k8-15)
    short8 qf[4];
    f32x16 acc[4];
    f32x16 zc = {0.f,0.f,0.f,0.f,0.f,0.f,0.f,0.f,0.f,0.f,0.f,0.f,0.f,0.f,0.f,0.f};
    f32x16 sb = {PBIASM,PBIASM,PBIASM,PBIASM,PBIASM,PBIASM,PBIASM,PBIASM,
                 PBIASM,PBIASM,PBIASM,PBIASM,PBIASM,PBIASM,PBIASM,PBIASM};
    #pragma unroll
    for (int t = 0; t < 4; ++t) {
        int qb = qt * 32 + t * 512;
        qf[t]  = *(const short8*)(Qb + (size_t)(qb + l31) * 16 + half * 8);
        acc[t] = zc;
    }

    // prefetch iteration 0 (64 keys: sub-steps A and B)
    short8 kfA = Kb[l31],      kfB = Kb[32 + l31];
    short8 vaA = *(const short8*)(Vr);
    short8 vcA = *(const short8*)(Vr + 16);
    short8 vaB = *(const short8*)(Vr + 32);
    short8 vcB = *(const short8*)(Vr + 48);

    for (int c0 = 0; c0 < kend; c0 += 64) {
        int c1 = c0 + 64;   // final prefetch reads stray in-ws bytes, never consumed
        short8 kfA_n = Kb[c1 + l31];
        short8 kfB_n = Kb[c1 + 32 + l31];
        short8 vaA_n = *(const short8*)(Vr + c1);
        short8 vcA_n = *(const short8*)(Vr + c1 + 16);
        short8 vaB_n = *(const short8*)(Vr + c1 + 32);
        short8 vcB_n = *(const short8*)(Vr + c1 + 48);

        // 4 independent q-tile chains; d consumed immediately (low liveness)
        #pragma unroll
        for (int t = 0; t < 4; ++t) {
            // S^T + magic: D = MAGIC + 128*score + bias; col=q, key=(reg&3)+8*(reg>>2)+4*half
            f32x16 dA = __builtin_amdgcn_mfma_f32_32x32x16_bf16(kfA, qf[t], sb, 0, 0, 0);
            unsigned p0[4], p1[4];
            #pragma unroll
            for (int r = 0; r < 4; ++r) {
                p0[r] = pk_pbits(dA[2 * r],     dA[2 * r + 1]);
                p1[r] = pk_pbits(dA[2 * r + 8], dA[2 * r + 9]);
            }
            short8 f0, f1;
            __builtin_memcpy(&f0, p0, 16);
            __builtin_memcpy(&f1, p1, 16);
            acc[t] = __builtin_amdgcn_mfma_f32_32x32x16_bf16(vaA, f0, acc[t], 0, 0, 0);
            acc[t] = __builtin_amdgcn_mfma_f32_32x32x16_bf16(vcA, f1, acc[t], 0, 0, 0);

            f32x16 dB = __builtin_amdgcn_mfma_f32_32x32x16_bf16(kfB, qf[t], sb, 0, 0, 0);
            #pragma unroll
            for (int r = 0; r < 4; ++r) {
                p0[r] = pk_pbits(dB[2 * r],     dB[2 * r + 1]);
                p1[r] = pk_pbits(dB[2 * r + 8], dB[2 * r + 9]);
            }
            __builtin_memcpy(&f0, p0, 16);
            __builtin_memcpy(&f1, p1, 16);
            acc[t] = __builtin_amdgcn_mfma_f32_32x32x16_bf16(vaB, f0, acc[t], 0, 0, 0);
            acc[t] = __builtin_amdgcn_mfma_f32_32x32x16_bf16(vcB, f1, acc[t], 0, 0, 0);
        }

        kfA = kfA_n; kfB = kfB_n;
        vaA = vaA_n; vcA = vcA_n; vaB = vaB_n; vcB = vcB_n;
    }

    // D rows: dim0-3 = half0 regs 0-3; dim4 = half1 reg0; l (row5) = half1 reg1
    float* base0 = pre + (((size_t)p * B + b) * H + h) * SEQ * PRE8;
    #pragma unroll
    for (int t = 0; t < 4; ++t) {
        int qb = qt * 32 + t * 512;
        float lv  = __shfl(acc[t][1], 32 + l31, 64);
        float inv = 1.0f / lv;
        float* dst = base0 + (size_t)(qb + l31) * PRE8;
        if (half == 0)
            *(float4*)dst = make_float4(acc[t][0]*inv, acc[t][1]*inv,
                                        acc[t][2]*inv, acc[t][3]*inv);
        else
            dst[4] = acc[t][0] * inv;
    }
}

// ---------------- sum 6 pairs + output projection ----------------
__global__ __launch_bounds__(256) void final_kernel(
    const float* __restrict__ pre,
    const float* __restrict__ W3, const float* __restrict__ b3,
    float* __restrict__ out)
{
    __shared__ float Ws[DIM * DIM];
    __shared__ float bs[DIM];
    int tid = threadIdx.x;
    for (int i = tid; i < DIM * DIM; i += 256) Ws[i] = W3[i];
    if (tid < DIM) bs[tid] = b3[tid];
    __syncthreads();

    int g = blockIdx.x * 256 + tid;      // B*SEQ = 16384 exactly
    int b = g / SEQ;
    int s = g - b * SEQ;

    float x[DIM];
    #pragma unroll
    for (int i = 0; i < DIM; ++i) x[i] = 0.f;

    for (int p = 0; p < 6; ++p) {
        #pragma unroll
        for (int h = 0; h < H; ++h) {
            const float* sr = pre + (((size_t)p * B + b) * H + h) * SEQ * PRE8
                                  + (size_t)s * PRE8;
            float4 a = *(const float4*)sr;
            float  a4 = sr[4];
            x[h * DKN + 0] += a.x; x[h * DKN + 1] += a.y; x[h * DKN + 2] += a.z;
            x[h * DKN + 3] += a.w; x[h * DKN + 4] += a4;
        }
    }

    float y[DIM];
    for (int j = 0; j < DIM; ++j) {
        float acc = bs[j];
        const float4* wr = (const float4*)&Ws[j * DIM];
        #pragma unroll
        for (int i4 = 0; i4 < 5; ++i4) {
            float4 w = wr[i4];
            acc += x[i4*4+0]*w.x + x[i4*4+1]*w.y + x[i4*4+2]*w.z + x[i4*4+3]*w.w;
        }
        y[j] = acc;
    }
    float4* dst = (float4*)(out + (size_t)(b * SEQ + s) * DIM);
    #pragma unroll
    for (int j4 = 0; j4 < 5; ++j4)
        dst[j4] = make_float4(y[j4*4+0], y[j4*4+1], y[j4*4+2], y[j4*4+3]);
}

extern "C" void kernel_launch(void* const* d_in, const int* in_sizes, int n_in,
                              void* d_out, int out_size, void* d_ws, size_t ws_size,
                              hipStream_t stream) {
    const float* q    = (const float*)d_in[0];
    const float* k    = (const float*)d_in[1];
    const float* v    = (const float*)d_in[2];
    const int*   mask = (const int*)d_in[3];
    const float* W0 = (const float*)d_in[4];  const float* b0 = (const float*)d_in[5];
    const float* W1 = (const float*)d_in[6];  const float* b1 = (const float*)d_in[7];
    const float* W2 = (const float*)d_in[8];  const float* b2 = (const float*)d_in[9];
    const float* W3 = (const float*)d_in[10]; const float* b3 = (const float*)d_in[11];

    const size_t NROW = (size_t)3 * B * H * SEQ;       // 196608
    short* Qt = (short*)d_ws;                          // NROW*16 shorts (6 MB)
    short* Kt = Qt + NROW * 16;                        // NROW*8 shorts  (3 MB)
    short* Vt = Kt + NROW * 8;                         // NROW*8 shorts  (3 MB)
    float* pre = (float*)(Vt + NROW * 8);              // 6*B*H*SEQ*8 floats (12.6 MB)
    int*   meta = (int*)(pre + (size_t)6 * B * H * SEQ * PRE8);
    float* out = (float*)d_out;

    proj_kernel<<<dim3(3 * B * H * (SEQ / 256)), dim3(256), 0, stream>>>(
        q, k, v, W0, b0, W1, b1, W2, b2, mask, Qt, Kt, Vt, meta);
    attn_kernel<<<dim3(6 * B * H * 16 / 2), dim3(128), 0, stream>>>(
        Qt, Kt, Vt, meta, pre);
    final_kernel<<<dim3(B * SEQ / 256), dim3(256), 0, stream>>>(pre, W3, b3, out);
}